// Round 1
// baseline (724.400 us; speedup 1.0000x reference)
//
#include <hip/hip_runtime.h>
#include <math.h>

#define NN 50000
#define NE 800000

// ---------------- degree count ----------------
__global__ void k_deg(const int* __restrict__ dst, int e_cnt, int* __restrict__ cnt) {
  int e = blockIdx.x * 256 + threadIdx.x;
  if (e < e_cnt) atomicAdd(&cnt[dst[e]], 1);
}

// ---------------- exclusive scan (single block) ----------------
__global__ __launch_bounds__(1024) void k_scan(const int* __restrict__ cnt, int n,
                                               int* __restrict__ offs,
                                               float* __restrict__ invd) {
  __shared__ int sd[1024];
  __shared__ int carry;
  int tid = threadIdx.x;
  if (tid == 0) carry = 0;
  __syncthreads();
  for (int base = 0; base < n; base += 1024) {
    int i = base + tid;
    int v = (i < n) ? cnt[i] : 0;
    sd[tid] = v;
    __syncthreads();
    for (int ofs = 1; ofs < 1024; ofs <<= 1) {
      int t = (tid >= ofs) ? sd[tid - ofs] : 0;
      __syncthreads();
      sd[tid] += t;
      __syncthreads();
    }
    if (i < n) {
      offs[i] = carry + sd[tid] - v;           // exclusive
      invd[i] = 1.0f / fmaxf((float)v, 1.0f);
    }
    __syncthreads();
    if (tid == 0) carry += sd[1023];
    __syncthreads();
  }
  if (tid == 0) offs[n] = carry;
}

// ---------------- scatter edges into CSR ----------------
__global__ void k_scatter(const int* __restrict__ src, const int* __restrict__ dst, int e_cnt,
                          int* __restrict__ cursor, int* __restrict__ csr) {
  int e = blockIdx.x * 256 + threadIdx.x;
  if (e < e_cnt) {
    int d = dst[e];
    int p = atomicAdd(&cursor[d], 1);
    csr[p] = src[e];
  }
}

// ---------------- per-node mean aggregation (wave per node, lane = channel) ----------------
__global__ __launch_bounds__(256) void k_aggregate(const float* __restrict__ feat,
                                                   const int* __restrict__ offs,
                                                   const int* __restrict__ csr,
                                                   const float* __restrict__ invd,
                                                   float* __restrict__ mean, int n) {
  int node = blockIdx.x * 4 + (threadIdx.x >> 6);
  int lane = threadIdx.x & 63;
  if (node >= n) return;
  int s = offs[node], e = offs[node + 1];
  float acc = 0.0f;
  for (int p = s; p < e; ++p) {
    int j = csr[p];                         // same addr across wave -> broadcast
    acc += feat[(size_t)j * 64 + lane];     // coalesced 256B row
  }
  mean[(size_t)node * 64 + lane] = acc * invd[node];
}

// ---------------- fused multi-source linear: out = act( sum_s g_s * A_s @ W_s + bias ) ----
// A_s: [n, 64] with row stride stride_s; W_s: [64,64] row-major.
struct LinArgs {
  const float* a[6];
  const float* w[6];
  int gidx[6];        // index into skip (flattened 3x3), or -1 => gate 1.0
  int stride[6];
  int nsrc;
  const float* bias;  // [64], required
  const float* skip;  // [9]
  float* out;         // [n,64]
  int n;
  int relu;
};

__global__ __launch_bounds__(256) void k_linear(LinArgs A) {
  __shared__ float sAT[64][68];   // [k][node], +4 pad keeps float4 align, tames conflicts
  const int t   = threadIdx.x;
  const int tx  = t & 15;         // ch group
  const int ty  = t >> 4;         // node group (and staging row group)
  const int ch0 = tx * 4;
  const int nn0 = ty * 4;
  const int n0  = blockIdx.x * 64;

  float acc[4][4];
#pragma unroll
  for (int m = 0; m < 4; ++m)
#pragma unroll
    for (int c = 0; c < 4; ++c) acc[m][c] = 0.0f;

  for (int s = 0; s < A.nsrc; ++s) {
    float gs = 1.0f;
    if (A.gidx[s] >= 0) {
      float sv = A.skip[A.gidx[s]];
      gs = 1.0f / (1.0f + expf(-sv));
    }
    const float* a  = A.a[s];
    const int    st = A.stride[s];
    __syncthreads();   // protect sAT from previous source's readers
#pragma unroll
    for (int i = 0; i < 4; ++i) {
      int r  = ty + 16 * i;
      int gr = n0 + r;
      float4 v = make_float4(0.f, 0.f, 0.f, 0.f);
      if (gr < A.n) v = *(const float4*)(a + (size_t)gr * st + ch0);
      sAT[ch0 + 0][r] = v.x * gs;
      sAT[ch0 + 1][r] = v.y * gs;
      sAT[ch0 + 2][r] = v.z * gs;
      sAT[ch0 + 3][r] = v.w * gs;
    }
    __syncthreads();
    const float* w = A.w[s];
#pragma unroll 4
    for (int k = 0; k < 64; ++k) {
      float4 wv = *(const float4*)(w + k * 64 + ch0);
      float4 av = *(const float4*)(&sAT[k][nn0]);
      acc[0][0] += av.x * wv.x; acc[0][1] += av.x * wv.y; acc[0][2] += av.x * wv.z; acc[0][3] += av.x * wv.w;
      acc[1][0] += av.y * wv.x; acc[1][1] += av.y * wv.y; acc[1][2] += av.y * wv.z; acc[1][3] += av.y * wv.w;
      acc[2][0] += av.z * wv.x; acc[2][1] += av.z * wv.y; acc[2][2] += av.z * wv.z; acc[2][3] += av.z * wv.w;
      acc[3][0] += av.w * wv.x; acc[3][1] += av.w * wv.y; acc[3][2] += av.w * wv.z; acc[3][3] += av.w * wv.w;
    }
  }

  float4 bv = *(const float4*)(A.bias + ch0);
#pragma unroll
  for (int m = 0; m < 4; ++m) {
    int node = n0 + nn0 + m;
    if (node < A.n) {
      float4 o;
      o.x = acc[m][0] + bv.x;
      o.y = acc[m][1] + bv.y;
      o.z = acc[m][2] + bv.z;
      o.w = acc[m][3] + bv.w;
      if (A.relu) {
        o.x = fmaxf(o.x, 0.f); o.y = fmaxf(o.y, 0.f);
        o.z = fmaxf(o.z, 0.f); o.w = fmaxf(o.w, 0.f);
      }
      *(float4*)(A.out + (size_t)node * 64 + ch0) = o;
    }
  }
}

// ---------------- column sums of the 4 embedding buffers -> s[256] ----------------
__global__ __launch_bounds__(256) void k_colsum(const float* __restrict__ x,
                                                const float* __restrict__ h0,
                                                const float* __restrict__ h1,
                                                const float* __restrict__ h2,
                                                int n, float* __restrict__ outp) {
  int lane = threadIdx.x & 63;
  int grp  = threadIdx.x >> 6;
  const float* bufs[4] = {x, h0, h1, h2};
  float acc[4] = {0.f, 0.f, 0.f, 0.f};
  for (int node = blockIdx.x * 4 + grp; node < n; node += gridDim.x * 4) {
#pragma unroll
    for (int b = 0; b < 4; ++b) acc[b] += bufs[b][(size_t)node * 64 + lane];
  }
  __shared__ float red[4][4][64];
#pragma unroll
  for (int b = 0; b < 4; ++b) red[b][grp][lane] = acc[b];
  __syncthreads();
  if (grp == 0) {
#pragma unroll
    for (int b = 0; b < 4; ++b) {
      float v = red[b][0][lane] + red[b][1][lane] + red[b][2][lane] + red[b][3][lane];
      atomicAdd(&outp[b * 64 + lane], v);
    }
  }
}

// ---------------- tiny post-MLP (single block) ----------------
__global__ __launch_bounds__(256) void k_post(const float* __restrict__ s,
                                              const float* __restrict__ w1, const float* __restrict__ b1,
                                              const float* __restrict__ w2, const float* __restrict__ b2,
                                              const float* __restrict__ w3, const float* __restrict__ b3,
                                              const float* __restrict__ w4, const float* __restrict__ b4,
                                              float* __restrict__ outp) {
  __shared__ float sh[256], h1[64], h2[64], h3[256];
  int t = threadIdx.x;
  sh[t] = s[t];
  __syncthreads();
  if (t < 64) {
    float a = b1[t];
    for (int k = 0; k < 256; ++k) a += sh[k] * w1[k * 64 + t];
    h1[t] = (a >= 0.f) ? a : 0.1f * a;   // leaky_relu 0.1
  }
  __syncthreads();
  if (t < 64) {
    float a = b2[t];
    for (int k = 0; k < 64; ++k) a += h1[k] * w2[k * 64 + t];
    h2[t] = fmaxf(a, 0.f);
  }
  __syncthreads();
  {
    float a = b3[t];
    for (int k = 0; k < 64; ++k) a += h2[k] * w3[k * 256 + t];
    h3[t] = fmaxf(a, 0.f);
  }
  __syncthreads();
  if (t < 64) {
    float a = b4[t];
    for (int k = 0; k < 256; ++k) a += h3[k] * w4[k * 64 + t];
    outp[t] = a;
  }
}

extern "C" void kernel_launch(void* const* d_in, const int* in_sizes, int n_in,
                              void* d_out, int out_size, void* d_ws, size_t ws_size,
                              hipStream_t stream) {
  const float* nf     = (const float*)d_in[0];
  const int*   ei     = (const int*)d_in[1];
  const float* pre_w1 = (const float*)d_in[2];
  const float* pre_b1 = (const float*)d_in[3];
  const float* pre_w2 = (const float*)d_in[4];
  const float* pre_b2 = (const float*)d_in[5];
  const float* skip   = (const float*)d_in[6];
  const float* wl0 = (const float*)d_in[7],  *bl0 = (const float*)d_in[8],  *wr0 = (const float*)d_in[9];
  const float* wl1 = (const float*)d_in[10], *bl1 = (const float*)d_in[11], *wr1 = (const float*)d_in[12];
  const float* wl2 = (const float*)d_in[13], *bl2 = (const float*)d_in[14], *wr2 = (const float*)d_in[15];
  const float* pw1 = (const float*)d_in[16], *pb1 = (const float*)d_in[17];
  const float* pw2 = (const float*)d_in[18], *pb2 = (const float*)d_in[19];
  const float* pw3 = (const float*)d_in[20], *pb3 = (const float*)d_in[21];
  const float* pw4 = (const float*)d_in[22], *pb4 = (const float*)d_in[23];
  float* out = (float*)d_out;

  const int N = NN, E = NE;

  // workspace carve-up
  char* ws = (char*)d_ws;
  size_t pos = 0;
  auto alloc = [&](size_t bytes) {
    char* p = ws + pos;
    pos += (bytes + 255) & ~(size_t)255;
    return (void*)p;
  };
  int*   cnt    = (int*)alloc((size_t)N * 4);
  int*   offs   = (int*)alloc((size_t)(N + 1) * 4);
  int*   cursor = (int*)alloc((size_t)N * 4);
  int*   csr    = (int*)alloc((size_t)E * 4);
  float* invd   = (float*)alloc((size_t)N * 4);
  const size_t FB = (size_t)N * 64 * 4;
  float* x  = (float*)alloc(FB);
  float* h0 = (float*)alloc(FB);
  float* h1 = (float*)alloc(FB);
  float* h2 = (float*)alloc(FB);
  float* m0 = (float*)alloc(FB);
  float* m1 = (float*)alloc(FB);
  float* m2 = (float*)alloc(FB);
  float* t0 = m2;                 // pre-MLP hidden; dead before m2 is written
  float* sv = (float*)alloc(256 * 4);

  hipMemsetAsync(cnt, 0, (size_t)N * 4, stream);
  hipMemsetAsync(sv, 0, 256 * 4, stream);

  const int* e_src = ei;
  const int* e_dst = ei + E;
  k_deg<<<(E + 255) / 256, 256, 0, stream>>>(e_dst, E, cnt);
  k_scan<<<1, 1024, 0, stream>>>(cnt, N, offs, invd);
  hipMemcpyAsync(cursor, offs, (size_t)N * 4, hipMemcpyDeviceToDevice, stream);
  k_scatter<<<(E + 255) / 256, 256, 0, stream>>>(e_src, e_dst, E, cursor, csr);

  const int LGRID = (N + 63) / 64;
  auto lin = [&](int nsrc,
                 const float* a0, int s0, const float* w0, int g0,
                 const float* a1, int s1, const float* w1_, int g1,
                 const float* a2, int s2, const float* w2_, int g2,
                 const float* a3, int s3, const float* w3_, int g3,
                 const float* a4, int s4, const float* w4_, int g4,
                 const float* a5, int s5, const float* w5_, int g5,
                 const float* bias, float* outp, int relu) {
    LinArgs A;
    A.a[0] = a0; A.a[1] = a1; A.a[2] = a2; A.a[3] = a3; A.a[4] = a4; A.a[5] = a5;
    A.w[0] = w0; A.w[1] = w1_; A.w[2] = w2_; A.w[3] = w3_; A.w[4] = w4_; A.w[5] = w5_;
    A.gidx[0] = g0; A.gidx[1] = g1; A.gidx[2] = g2; A.gidx[3] = g3; A.gidx[4] = g4; A.gidx[5] = g5;
    A.stride[0] = s0; A.stride[1] = s1; A.stride[2] = s2; A.stride[3] = s3; A.stride[4] = s4; A.stride[5] = s5;
    A.nsrc = nsrc; A.bias = bias; A.skip = skip; A.out = outp; A.n = N; A.relu = relu;
    k_linear<<<LGRID, 256, 0, stream>>>(A);
  };

  // pre_mlp: t0 = relu(nf @ pre_w1 + pre_b1)   (K=128 -> two 64-row blocks)
  lin(2, nf, 128, pre_w1, -1, nf + 64, 128, pre_w1 + 64 * 64, -1,
      nullptr, 0, nullptr, -1, nullptr, 0, nullptr, -1, nullptr, 0, nullptr, -1,
      nullptr, 0, nullptr, -1, pre_b1, t0, 1);
  // x = t0 @ pre_w2 + pre_b2
  lin(1, t0, 64, pre_w2, -1,
      nullptr, 0, nullptr, -1, nullptr, 0, nullptr, -1, nullptr, 0, nullptr, -1,
      nullptr, 0, nullptr, -1, nullptr, 0, nullptr, -1, pre_b2, x, 0);

  // layer 0
  k_aggregate<<<(N + 3) / 4, 256, 0, stream>>>(x, offs, csr, invd, m0, N);
  lin(2, m0, 64, wl0, 0, x, 64, wr0, 0,
      nullptr, 0, nullptr, -1, nullptr, 0, nullptr, -1, nullptr, 0, nullptr, -1,
      nullptr, 0, nullptr, -1, bl0, h0, 1);

  // layer 1 (gates skip[1][0]=idx3, skip[1][1]=idx4)
  k_aggregate<<<(N + 3) / 4, 256, 0, stream>>>(h0, offs, csr, invd, m1, N);
  lin(4, m0, 64, wl1, 3, m1, 64, wl1 + 64 * 64, 4,
      x, 64, wr1, 3, h0, 64, wr1 + 64 * 64, 4,
      nullptr, 0, nullptr, -1, nullptr, 0, nullptr, -1, bl1, h1, 1);

  // layer 2 (gates skip[2][0..2] = idx 6,7,8)
  k_aggregate<<<(N + 3) / 4, 256, 0, stream>>>(h1, offs, csr, invd, m2, N);
  lin(6, m0, 64, wl2, 6, m1, 64, wl2 + 64 * 64, 7, m2, 64, wl2 + 128 * 64, 8,
      x, 64, wr2, 6, h0, 64, wr2 + 64 * 64, 7, h1, 64, wr2 + 128 * 64, 8,
      bl2, h2, 1);

  // s = column sums of [x|h0|h1|h2]; then post-MLP
  k_colsum<<<256, 256, 0, stream>>>(x, h0, h1, h2, N, sv);
  k_post<<<1, 256, 0, stream>>>(sv, pw1, pb1, pw2, pb2, pw3, pb3, pw4, pb4, out);
}

// Round 2
// 637.305 us; speedup vs baseline: 1.1367x; 1.1367x over previous
//
#include <hip/hip_runtime.h>
#include <math.h>

#define NN 50000
#define NE 800000

// ---------------- degree count ----------------
__global__ void k_deg(const int* __restrict__ dst, int e_cnt, int* __restrict__ cnt) {
  int e = blockIdx.x * 256 + threadIdx.x;
  if (e < e_cnt) atomicAdd(&cnt[dst[e]], 1);
}

// ---------------- two-level exclusive scan ----------------
// Phase 1: per-block (256 elems) reduction -> bsum[b]
__global__ __launch_bounds__(256) void k_blockred(const int* __restrict__ cnt, int n,
                                                  int* __restrict__ bsum) {
  __shared__ int sd[256];
  int t = threadIdx.x;
  int i = blockIdx.x * 256 + t;
  sd[t] = (i < n) ? cnt[i] : 0;
  __syncthreads();
  for (int o = 128; o > 0; o >>= 1) {
    if (t < o) sd[t] += sd[t + o];
    __syncthreads();
  }
  if (t == 0) bsum[blockIdx.x] = sd[0];
}

// Phase 2: single block scans the <=256 block sums (exclusive, in place); writes total
__global__ __launch_bounds__(256) void k_scanb(int* __restrict__ bsum, int nb,
                                               int* __restrict__ total) {
  __shared__ int sd[256];
  int t = threadIdx.x;
  int v = (t < nb) ? bsum[t] : 0;
  sd[t] = v;
  __syncthreads();
  for (int o = 1; o < 256; o <<= 1) {
    int u = (t >= o) ? sd[t - o] : 0;
    __syncthreads();
    sd[t] += u;
    __syncthreads();
  }
  if (t < nb) bsum[t] = sd[t] - v;   // exclusive
  if (t == 255) *total = sd[255];
}

// Phase 3: per-block local exclusive scan + block offset; also writes cursor & invd
__global__ __launch_bounds__(256) void k_scanfinal(const int* __restrict__ cnt, int n,
                                                   const int* __restrict__ bsum,
                                                   int* __restrict__ offs,
                                                   int* __restrict__ cursor,
                                                   float* __restrict__ invd) {
  __shared__ int sd[256];
  int t = threadIdx.x;
  int i = blockIdx.x * 256 + t;
  int v = (i < n) ? cnt[i] : 0;
  sd[t] = v;
  __syncthreads();
  for (int o = 1; o < 256; o <<= 1) {
    int u = (t >= o) ? sd[t - o] : 0;
    __syncthreads();
    sd[t] += u;
    __syncthreads();
  }
  if (i < n) {
    int off = bsum[blockIdx.x] + sd[t] - v;
    offs[i]   = off;
    cursor[i] = off;
    invd[i]   = 1.0f / fmaxf((float)v, 1.0f);
  }
}

// ---------------- scatter edges into CSR ----------------
__global__ void k_scatter(const int* __restrict__ src, const int* __restrict__ dst, int e_cnt,
                          int* __restrict__ cursor, int* __restrict__ csr) {
  int e = blockIdx.x * 256 + threadIdx.x;
  if (e < e_cnt) {
    int d = dst[e];
    int p = atomicAdd(&cursor[d], 1);
    csr[p] = src[e];
  }
}

// ---------------- per-node mean aggregation (wave per node, lane = channel) ----------------
__global__ __launch_bounds__(256) void k_aggregate(const float* __restrict__ feat,
                                                   const int* __restrict__ offs,
                                                   const int* __restrict__ csr,
                                                   const float* __restrict__ invd,
                                                   float* __restrict__ mean, int n) {
  int node = blockIdx.x * 4 + (threadIdx.x >> 6);
  int lane = threadIdx.x & 63;
  if (node >= n) return;
  int s = offs[node], e = offs[node + 1];
  float acc = 0.0f;
  for (int p = s; p < e; ++p) {
    int j = csr[p];                         // same addr across wave -> broadcast
    acc += feat[(size_t)j * 64 + lane];     // coalesced 256B row
  }
  mean[(size_t)node * 64 + lane] = acc * invd[node];
}

// ---------------- fused multi-source linear: out = act( sum_s g_s * A_s @ W_s + bias ) ----
// A_s: [n, 64] with row stride stride_s; W_s: [64,64] row-major.
struct LinArgs {
  const float* a[6];
  const float* w[6];
  int gidx[6];        // index into skip (flattened 3x3), or -1 => gate 1.0
  int stride[6];
  int nsrc;
  const float* bias;  // [64], required
  const float* skip;  // [9]
  float* out;         // [n,64]
  int n;
  int relu;
};

__global__ __launch_bounds__(256) void k_linear(LinArgs A) {
  __shared__ float sAT[64][68];   // [k][node], +4 pad keeps float4 align, tames conflicts
  const int t   = threadIdx.x;
  const int tx  = t & 15;         // ch group
  const int ty  = t >> 4;         // node group (and staging row group)
  const int ch0 = tx * 4;
  const int nn0 = ty * 4;
  const int n0  = blockIdx.x * 64;

  float acc[4][4];
#pragma unroll
  for (int m = 0; m < 4; ++m)
#pragma unroll
    for (int c = 0; c < 4; ++c) acc[m][c] = 0.0f;

  for (int s = 0; s < A.nsrc; ++s) {
    float gs = 1.0f;
    if (A.gidx[s] >= 0) {
      float sv = A.skip[A.gidx[s]];
      gs = 1.0f / (1.0f + expf(-sv));
    }
    const float* a  = A.a[s];
    const int    st = A.stride[s];
    __syncthreads();   // protect sAT from previous source's readers
#pragma unroll
    for (int i = 0; i < 4; ++i) {
      int r  = ty + 16 * i;
      int gr = n0 + r;
      float4 v = make_float4(0.f, 0.f, 0.f, 0.f);
      if (gr < A.n) v = *(const float4*)(a + (size_t)gr * st + ch0);
      sAT[ch0 + 0][r] = v.x * gs;
      sAT[ch0 + 1][r] = v.y * gs;
      sAT[ch0 + 2][r] = v.z * gs;
      sAT[ch0 + 3][r] = v.w * gs;
    }
    __syncthreads();
    const float* w = A.w[s];
#pragma unroll 4
    for (int k = 0; k < 64; ++k) {
      float4 wv = *(const float4*)(w + k * 64 + ch0);
      float4 av = *(const float4*)(&sAT[k][nn0]);
      acc[0][0] += av.x * wv.x; acc[0][1] += av.x * wv.y; acc[0][2] += av.x * wv.z; acc[0][3] += av.x * wv.w;
      acc[1][0] += av.y * wv.x; acc[1][1] += av.y * wv.y; acc[1][2] += av.y * wv.z; acc[1][3] += av.y * wv.w;
      acc[2][0] += av.z * wv.x; acc[2][1] += av.z * wv.y; acc[2][2] += av.z * wv.z; acc[2][3] += av.z * wv.w;
      acc[3][0] += av.w * wv.x; acc[3][1] += av.w * wv.y; acc[3][2] += av.w * wv.z; acc[3][3] += av.w * wv.w;
    }
  }

  float4 bv = *(const float4*)(A.bias + ch0);
#pragma unroll
  for (int m = 0; m < 4; ++m) {
    int node = n0 + nn0 + m;
    if (node < A.n) {
      float4 o;
      o.x = acc[m][0] + bv.x;
      o.y = acc[m][1] + bv.y;
      o.z = acc[m][2] + bv.z;
      o.w = acc[m][3] + bv.w;
      if (A.relu) {
        o.x = fmaxf(o.x, 0.f); o.y = fmaxf(o.y, 0.f);
        o.z = fmaxf(o.z, 0.f); o.w = fmaxf(o.w, 0.f);
      }
      *(float4*)(A.out + (size_t)node * 64 + ch0) = o;
    }
  }
}

// ---------------- column sums of the 4 embedding buffers -> s[256] ----------------
__global__ __launch_bounds__(256) void k_colsum(const float* __restrict__ x,
                                                const float* __restrict__ h0,
                                                const float* __restrict__ h1,
                                                const float* __restrict__ h2,
                                                int n, float* __restrict__ outp) {
  int lane = threadIdx.x & 63;
  int grp  = threadIdx.x >> 6;
  const float* bufs[4] = {x, h0, h1, h2};
  float acc[4] = {0.f, 0.f, 0.f, 0.f};
  for (int node = blockIdx.x * 4 + grp; node < n; node += gridDim.x * 4) {
#pragma unroll
    for (int b = 0; b < 4; ++b) acc[b] += bufs[b][(size_t)node * 64 + lane];
  }
  __shared__ float red[4][4][64];
#pragma unroll
  for (int b = 0; b < 4; ++b) red[b][grp][lane] = acc[b];
  __syncthreads();
  if (grp == 0) {
#pragma unroll
    for (int b = 0; b < 4; ++b) {
      float v = red[b][0][lane] + red[b][1][lane] + red[b][2][lane] + red[b][3][lane];
      atomicAdd(&outp[b * 64 + lane], v);
    }
  }
}

// ---------------- tiny post-MLP (single block) ----------------
__global__ __launch_bounds__(256) void k_post(const float* __restrict__ s,
                                              const float* __restrict__ w1, const float* __restrict__ b1,
                                              const float* __restrict__ w2, const float* __restrict__ b2,
                                              const float* __restrict__ w3, const float* __restrict__ b3,
                                              const float* __restrict__ w4, const float* __restrict__ b4,
                                              float* __restrict__ outp) {
  __shared__ float sh[256], h1[64], h2[64], h3[256];
  int t = threadIdx.x;
  sh[t] = s[t];
  __syncthreads();
  if (t < 64) {
    float a = b1[t];
    for (int k = 0; k < 256; ++k) a += sh[k] * w1[k * 64 + t];
    h1[t] = (a >= 0.f) ? a : 0.1f * a;   // leaky_relu 0.1
  }
  __syncthreads();
  if (t < 64) {
    float a = b2[t];
    for (int k = 0; k < 64; ++k) a += h1[k] * w2[k * 64 + t];
    h2[t] = fmaxf(a, 0.f);
  }
  __syncthreads();
  {
    float a = b3[t];
    for (int k = 0; k < 64; ++k) a += h2[k] * w3[k * 256 + t];
    h3[t] = fmaxf(a, 0.f);
  }
  __syncthreads();
  if (t < 64) {
    float a = b4[t];
    for (int k = 0; k < 256; ++k) a += h3[k] * w4[k * 64 + t];
    outp[t] = a;
  }
}

extern "C" void kernel_launch(void* const* d_in, const int* in_sizes, int n_in,
                              void* d_out, int out_size, void* d_ws, size_t ws_size,
                              hipStream_t stream) {
  const float* nf     = (const float*)d_in[0];
  const int*   ei     = (const int*)d_in[1];
  const float* pre_w1 = (const float*)d_in[2];
  const float* pre_b1 = (const float*)d_in[3];
  const float* pre_w2 = (const float*)d_in[4];
  const float* pre_b2 = (const float*)d_in[5];
  const float* skip   = (const float*)d_in[6];
  const float* wl0 = (const float*)d_in[7],  *bl0 = (const float*)d_in[8],  *wr0 = (const float*)d_in[9];
  const float* wl1 = (const float*)d_in[10], *bl1 = (const float*)d_in[11], *wr1 = (const float*)d_in[12];
  const float* wl2 = (const float*)d_in[13], *bl2 = (const float*)d_in[14], *wr2 = (const float*)d_in[15];
  const float* pw1 = (const float*)d_in[16], *pb1 = (const float*)d_in[17];
  const float* pw2 = (const float*)d_in[18], *pb2 = (const float*)d_in[19];
  const float* pw3 = (const float*)d_in[20], *pb3 = (const float*)d_in[21];
  const float* pw4 = (const float*)d_in[22], *pb4 = (const float*)d_in[23];
  float* out = (float*)d_out;

  const int N = NN, E = NE;
  const int NBLK = (N + 255) / 256;   // 196

  // workspace carve-up
  char* ws = (char*)d_ws;
  size_t pos = 0;
  auto alloc = [&](size_t bytes) {
    char* p = ws + pos;
    pos += (bytes + 255) & ~(size_t)255;
    return (void*)p;
  };
  int*   cnt    = (int*)alloc((size_t)N * 4);
  int*   offs   = (int*)alloc((size_t)(N + 1) * 4);
  int*   cursor = (int*)alloc((size_t)N * 4);
  int*   csr    = (int*)alloc((size_t)E * 4);
  float* invd   = (float*)alloc((size_t)N * 4);
  int*   bsum   = (int*)alloc((size_t)NBLK * 4);
  const size_t FB = (size_t)N * 64 * 4;
  float* x  = (float*)alloc(FB);
  float* h0 = (float*)alloc(FB);
  float* h1 = (float*)alloc(FB);
  float* h2 = (float*)alloc(FB);
  float* m0 = (float*)alloc(FB);
  float* m1 = (float*)alloc(FB);
  float* m2 = (float*)alloc(FB);
  float* t0 = m2;                 // pre-MLP hidden; dead before m2 is written
  float* sv = (float*)alloc(256 * 4);

  hipMemsetAsync(cnt, 0, (size_t)N * 4, stream);
  hipMemsetAsync(sv, 0, 256 * 4, stream);

  const int* e_src = ei;
  const int* e_dst = ei + E;
  k_deg<<<(E + 255) / 256, 256, 0, stream>>>(e_dst, E, cnt);
  k_blockred<<<NBLK, 256, 0, stream>>>(cnt, N, bsum);
  k_scanb<<<1, 256, 0, stream>>>(bsum, NBLK, offs + N);   // writes offs[N] = E total
  k_scanfinal<<<NBLK, 256, 0, stream>>>(cnt, N, bsum, offs, cursor, invd);
  k_scatter<<<(E + 255) / 256, 256, 0, stream>>>(e_src, e_dst, E, cursor, csr);

  const int LGRID = (N + 63) / 64;
  auto lin = [&](int nsrc,
                 const float* a0, int s0, const float* w0, int g0,
                 const float* a1, int s1, const float* w1_, int g1,
                 const float* a2, int s2, const float* w2_, int g2,
                 const float* a3, int s3, const float* w3_, int g3,
                 const float* a4, int s4, const float* w4_, int g4,
                 const float* a5, int s5, const float* w5_, int g5,
                 const float* bias, float* outp, int relu) {
    LinArgs A;
    A.a[0] = a0; A.a[1] = a1; A.a[2] = a2; A.a[3] = a3; A.a[4] = a4; A.a[5] = a5;
    A.w[0] = w0; A.w[1] = w1_; A.w[2] = w2_; A.w[3] = w3_; A.w[4] = w4_; A.w[5] = w5_;
    A.gidx[0] = g0; A.gidx[1] = g1; A.gidx[2] = g2; A.gidx[3] = g3; A.gidx[4] = g4; A.gidx[5] = g5;
    A.stride[0] = s0; A.stride[1] = s1; A.stride[2] = s2; A.stride[3] = s3; A.stride[4] = s4; A.stride[5] = s5;
    A.nsrc = nsrc; A.bias = bias; A.skip = skip; A.out = outp; A.n = N; A.relu = relu;
    k_linear<<<LGRID, 256, 0, stream>>>(A);
  };

  // pre_mlp: t0 = relu(nf @ pre_w1 + pre_b1)   (K=128 -> two 64-row blocks)
  lin(2, nf, 128, pre_w1, -1, nf + 64, 128, pre_w1 + 64 * 64, -1,
      nullptr, 0, nullptr, -1, nullptr, 0, nullptr, -1, nullptr, 0, nullptr, -1,
      nullptr, 0, nullptr, -1, pre_b1, t0, 1);
  // x = t0 @ pre_w2 + pre_b2
  lin(1, t0, 64, pre_w2, -1,
      nullptr, 0, nullptr, -1, nullptr, 0, nullptr, -1, nullptr, 0, nullptr, -1,
      nullptr, 0, nullptr, -1, nullptr, 0, nullptr, -1, pre_b2, x, 0);

  // layer 0
  k_aggregate<<<(N + 3) / 4, 256, 0, stream>>>(x, offs, csr, invd, m0, N);
  lin(2, m0, 64, wl0, 0, x, 64, wr0, 0,
      nullptr, 0, nullptr, -1, nullptr, 0, nullptr, -1, nullptr, 0, nullptr, -1,
      nullptr, 0, nullptr, -1, bl0, h0, 1);

  // layer 1 (gates skip[1][0]=idx3, skip[1][1]=idx4)
  k_aggregate<<<(N + 3) / 4, 256, 0, stream>>>(h0, offs, csr, invd, m1, N);
  lin(4, m0, 64, wl1, 3, m1, 64, wl1 + 64 * 64, 4,
      x, 64, wr1, 3, h0, 64, wr1 + 64 * 64, 4,
      nullptr, 0, nullptr, -1, nullptr, 0, nullptr, -1, bl1, h1, 1);

  // layer 2 (gates skip[2][0..2] = idx 6,7,8)
  k_aggregate<<<(N + 3) / 4, 256, 0, stream>>>(h1, offs, csr, invd, m2, N);
  lin(6, m0, 64, wl2, 6, m1, 64, wl2 + 64 * 64, 7, m2, 64, wl2 + 128 * 64, 8,
      x, 64, wr2, 6, h0, 64, wr2 + 64 * 64, 7, h1, 64, wr2 + 128 * 64, 8,
      bl2, h2, 1);

  // s = column sums of [x|h0|h1|h2]; then post-MLP
  k_colsum<<<256, 256, 0, stream>>>(x, h0, h1, h2, N, sv);
  k_post<<<1, 256, 0, stream>>>(sv, pw1, pb1, pw2, pb2, pw3, pb3, pw4, pb4, out);
}

// Round 3
// 496.207 us; speedup vs baseline: 1.4599x; 1.2844x over previous
//
#include <hip/hip_runtime.h>
#include <math.h>

#define NN 50000
#define NE 800000

// ---------------- degree count ----------------
__global__ void k_deg(const int* __restrict__ dst, int e_cnt, int* __restrict__ cnt) {
  int e = blockIdx.x * 256 + threadIdx.x;
  if (e < e_cnt) atomicAdd(&cnt[dst[e]], 1);
}

// ---------------- two-level exclusive scan ----------------
__global__ __launch_bounds__(256) void k_blockred(const int* __restrict__ cnt, int n,
                                                  int* __restrict__ bsum) {
  __shared__ int sd[256];
  int t = threadIdx.x;
  int i = blockIdx.x * 256 + t;
  sd[t] = (i < n) ? cnt[i] : 0;
  __syncthreads();
  for (int o = 128; o > 0; o >>= 1) {
    if (t < o) sd[t] += sd[t + o];
    __syncthreads();
  }
  if (t == 0) bsum[blockIdx.x] = sd[0];
}

__global__ __launch_bounds__(256) void k_scanb(int* __restrict__ bsum, int nb,
                                               int* __restrict__ total) {
  __shared__ int sd[256];
  int t = threadIdx.x;
  int v = (t < nb) ? bsum[t] : 0;
  sd[t] = v;
  __syncthreads();
  for (int o = 1; o < 256; o <<= 1) {
    int u = (t >= o) ? sd[t - o] : 0;
    __syncthreads();
    sd[t] += u;
    __syncthreads();
  }
  if (t < nb) bsum[t] = sd[t] - v;   // exclusive
  if (t == 255) *total = sd[255];
}

__global__ __launch_bounds__(256) void k_scanfinal(const int* __restrict__ cnt, int n,
                                                   const int* __restrict__ bsum,
                                                   int* __restrict__ offs,
                                                   int* __restrict__ cursor,
                                                   float* __restrict__ invd) {
  __shared__ int sd[256];
  int t = threadIdx.x;
  int i = blockIdx.x * 256 + t;
  int v = (i < n) ? cnt[i] : 0;
  sd[t] = v;
  __syncthreads();
  for (int o = 1; o < 256; o <<= 1) {
    int u = (t >= o) ? sd[t - o] : 0;
    __syncthreads();
    sd[t] += u;
    __syncthreads();
  }
  if (i < n) {
    int off = bsum[blockIdx.x] + sd[t] - v;
    offs[i]   = off;
    cursor[i] = off;
    invd[i]   = 1.0f / fmaxf((float)v, 1.0f);
  }
}

// ---------------- scatter edges into CSR ----------------
__global__ void k_scatter(const int* __restrict__ src, const int* __restrict__ dst, int e_cnt,
                          int* __restrict__ cursor, int* __restrict__ csr) {
  int e = blockIdx.x * 256 + threadIdx.x;
  if (e < e_cnt) {
    int d = dst[e];
    int p = atomicAdd(&cursor[d], 1);
    csr[p] = src[e];
  }
}

// ---------------- per-node mean aggregation ----------------
// One wave per node. lane = nsub*16 + cg; each iteration loads 8 neighbor rows
// (2-deep unroll x 4 parallel sub-slots), each row as 16 lanes x float4 (256B).
// Cross-lane reduce over nsub via shfl_xor(16), shfl_xor(32); lanes 0-15 write.
__global__ __launch_bounds__(256) void k_aggregate(const float* __restrict__ feat,
                                                   const int* __restrict__ offs,
                                                   const int* __restrict__ csr,
                                                   const float* __restrict__ invd,
                                                   float* __restrict__ mean, int n) {
  int node = blockIdx.x * 4 + (threadIdx.x >> 6);
  int lane = threadIdx.x & 63;
  int nsub = lane >> 4;        // 0..3: neighbor sub-slot
  int cg   = lane & 15;        // 0..15: float4 channel group
  if (node >= n) return;
  int s = offs[node], e = offs[node + 1];

  float ax = 0.f, ay = 0.f, az = 0.f, aw = 0.f;
  if (e > s) {
    int emax = e - 1;
    for (int p0 = s; p0 < e; p0 += 8) {
      int p1 = p0 + nsub;
      int p2 = p0 + 4 + nsub;
      // clamped, unguarded index loads keep all row loads in flight
      int j1 = csr[p1 < emax ? p1 : emax];
      int j2 = csr[p2 < emax ? p2 : emax];
      float4 v1 = *(const float4*)(feat + (size_t)j1 * 64 + cg * 4);
      float4 v2 = *(const float4*)(feat + (size_t)j2 * 64 + cg * 4);
      if (p1 < e) { ax += v1.x; ay += v1.y; az += v1.z; aw += v1.w; }
      if (p2 < e) { ax += v2.x; ay += v2.y; az += v2.z; aw += v2.w; }
    }
  }
  // reduce across the 4 neighbor sub-slots (lanes differing in bits 4,5)
  ax += __shfl_xor(ax, 16, 64); ax += __shfl_xor(ax, 32, 64);
  ay += __shfl_xor(ay, 16, 64); ay += __shfl_xor(ay, 32, 64);
  az += __shfl_xor(az, 16, 64); az += __shfl_xor(az, 32, 64);
  aw += __shfl_xor(aw, 16, 64); aw += __shfl_xor(aw, 32, 64);

  if (nsub == 0) {
    float d = invd[node];
    float4 o = make_float4(ax * d, ay * d, az * d, aw * d);
    *(float4*)(mean + (size_t)node * 64 + cg * 4) = o;
  }
}

// ---------------- fused multi-source linear: out = act( sum_s g_s * A_s @ W_s + bias ) ----
struct LinArgs {
  const float* a[6];
  const float* w[6];
  int gidx[6];        // index into skip (flattened 3x3), or -1 => gate 1.0
  int stride[6];
  int nsrc;
  const float* bias;  // [64], required
  const float* skip;  // [9]
  float* out;         // [n,64]
  int n;
  int relu;
};

__global__ __launch_bounds__(256) void k_linear(LinArgs A) {
  __shared__ float sAT[64][68];   // [k][node], +4 pad keeps float4 align, tames conflicts
  const int t   = threadIdx.x;
  const int tx  = t & 15;         // ch group
  const int ty  = t >> 4;         // node group (and staging row group)
  const int ch0 = tx * 4;
  const int nn0 = ty * 4;
  const int n0  = blockIdx.x * 64;

  float acc[4][4];
#pragma unroll
  for (int m = 0; m < 4; ++m)
#pragma unroll
    for (int c = 0; c < 4; ++c) acc[m][c] = 0.0f;

  for (int s = 0; s < A.nsrc; ++s) {
    float gs = 1.0f;
    if (A.gidx[s] >= 0) {
      float sv = A.skip[A.gidx[s]];
      gs = 1.0f / (1.0f + expf(-sv));
    }
    const float* a  = A.a[s];
    const int    st = A.stride[s];
    __syncthreads();   // protect sAT from previous source's readers
#pragma unroll
    for (int i = 0; i < 4; ++i) {
      int r  = ty + 16 * i;
      int gr = n0 + r;
      float4 v = make_float4(0.f, 0.f, 0.f, 0.f);
      if (gr < A.n) v = *(const float4*)(a + (size_t)gr * st + ch0);
      sAT[ch0 + 0][r] = v.x * gs;
      sAT[ch0 + 1][r] = v.y * gs;
      sAT[ch0 + 2][r] = v.z * gs;
      sAT[ch0 + 3][r] = v.w * gs;
    }
    __syncthreads();
    const float* w = A.w[s];
#pragma unroll 4
    for (int k = 0; k < 64; ++k) {
      float4 wv = *(const float4*)(w + k * 64 + ch0);
      float4 av = *(const float4*)(&sAT[k][nn0]);
      acc[0][0] += av.x * wv.x; acc[0][1] += av.x * wv.y; acc[0][2] += av.x * wv.z; acc[0][3] += av.x * wv.w;
      acc[1][0] += av.y * wv.x; acc[1][1] += av.y * wv.y; acc[1][2] += av.y * wv.z; acc[1][3] += av.y * wv.w;
      acc[2][0] += av.z * wv.x; acc[2][1] += av.z * wv.y; acc[2][2] += av.z * wv.z; acc[2][3] += av.z * wv.w;
      acc[3][0] += av.w * wv.x; acc[3][1] += av.w * wv.y; acc[3][2] += av.w * wv.z; acc[3][3] += av.w * wv.w;
    }
  }

  float4 bv = *(const float4*)(A.bias + ch0);
#pragma unroll
  for (int m = 0; m < 4; ++m) {
    int node = n0 + nn0 + m;
    if (node < A.n) {
      float4 o;
      o.x = acc[m][0] + bv.x;
      o.y = acc[m][1] + bv.y;
      o.z = acc[m][2] + bv.z;
      o.w = acc[m][3] + bv.w;
      if (A.relu) {
        o.x = fmaxf(o.x, 0.f); o.y = fmaxf(o.y, 0.f);
        o.z = fmaxf(o.z, 0.f); o.w = fmaxf(o.w, 0.f);
      }
      *(float4*)(A.out + (size_t)node * 64 + ch0) = o;
    }
  }
}

// ---------------- column sums of the 4 embedding buffers -> s[256] ----------------
__global__ __launch_bounds__(256) void k_colsum(const float* __restrict__ x,
                                                const float* __restrict__ h0,
                                                const float* __restrict__ h1,
                                                const float* __restrict__ h2,
                                                int n, float* __restrict__ outp) {
  int lane = threadIdx.x & 63;
  int grp  = threadIdx.x >> 6;
  const float* bufs[4] = {x, h0, h1, h2};
  float acc[4] = {0.f, 0.f, 0.f, 0.f};
  for (int node = blockIdx.x * 4 + grp; node < n; node += gridDim.x * 4) {
#pragma unroll
    for (int b = 0; b < 4; ++b) acc[b] += bufs[b][(size_t)node * 64 + lane];
  }
  __shared__ float red[4][4][64];
#pragma unroll
  for (int b = 0; b < 4; ++b) red[b][grp][lane] = acc[b];
  __syncthreads();
  if (grp == 0) {
#pragma unroll
    for (int b = 0; b < 4; ++b) {
      float v = red[b][0][lane] + red[b][1][lane] + red[b][2][lane] + red[b][3][lane];
      atomicAdd(&outp[b * 64 + lane], v);
    }
  }
}

// ---------------- tiny post-MLP (single block) ----------------
__global__ __launch_bounds__(256) void k_post(const float* __restrict__ s,
                                              const float* __restrict__ w1, const float* __restrict__ b1,
                                              const float* __restrict__ w2, const float* __restrict__ b2,
                                              const float* __restrict__ w3, const float* __restrict__ b3,
                                              const float* __restrict__ w4, const float* __restrict__ b4,
                                              float* __restrict__ outp) {
  __shared__ float sh[256], h1[64], h2[64], h3[256];
  int t = threadIdx.x;
  sh[t] = s[t];
  __syncthreads();
  if (t < 64) {
    float a = b1[t];
    for (int k = 0; k < 256; ++k) a += sh[k] * w1[k * 64 + t];
    h1[t] = (a >= 0.f) ? a : 0.1f * a;   // leaky_relu 0.1
  }
  __syncthreads();
  if (t < 64) {
    float a = b2[t];
    for (int k = 0; k < 64; ++k) a += h1[k] * w2[k * 64 + t];
    h2[t] = fmaxf(a, 0.f);
  }
  __syncthreads();
  {
    float a = b3[t];
    for (int k = 0; k < 64; ++k) a += h2[k] * w3[k * 256 + t];
    h3[t] = fmaxf(a, 0.f);
  }
  __syncthreads();
  if (t < 64) {
    float a = b4[t];
    for (int k = 0; k < 256; ++k) a += h3[k] * w4[k * 64 + t];
    outp[t] = a;
  }
}

extern "C" void kernel_launch(void* const* d_in, const int* in_sizes, int n_in,
                              void* d_out, int out_size, void* d_ws, size_t ws_size,
                              hipStream_t stream) {
  const float* nf     = (const float*)d_in[0];
  const int*   ei     = (const int*)d_in[1];
  const float* pre_w1 = (const float*)d_in[2];
  const float* pre_b1 = (const float*)d_in[3];
  const float* pre_w2 = (const float*)d_in[4];
  const float* pre_b2 = (const float*)d_in[5];
  const float* skip   = (const float*)d_in[6];
  const float* wl0 = (const float*)d_in[7],  *bl0 = (const float*)d_in[8],  *wr0 = (const float*)d_in[9];
  const float* wl1 = (const float*)d_in[10], *bl1 = (const float*)d_in[11], *wr1 = (const float*)d_in[12];
  const float* wl2 = (const float*)d_in[13], *bl2 = (const float*)d_in[14], *wr2 = (const float*)d_in[15];
  const float* pw1 = (const float*)d_in[16], *pb1 = (const float*)d_in[17];
  const float* pw2 = (const float*)d_in[18], *pb2 = (const float*)d_in[19];
  const float* pw3 = (const float*)d_in[20], *pb3 = (const float*)d_in[21];
  const float* pw4 = (const float*)d_in[22], *pb4 = (const float*)d_in[23];
  float* out = (float*)d_out;

  const int N = NN, E = NE;
  const int NBLK = (N + 255) / 256;   // 196

  // workspace carve-up
  char* ws = (char*)d_ws;
  size_t pos = 0;
  auto alloc = [&](size_t bytes) {
    char* p = ws + pos;
    pos += (bytes + 255) & ~(size_t)255;
    return (void*)p;
  };
  int*   cnt    = (int*)alloc((size_t)N * 4);
  int*   offs   = (int*)alloc((size_t)(N + 1) * 4);
  int*   cursor = (int*)alloc((size_t)N * 4);
  int*   csr    = (int*)alloc((size_t)E * 4);
  float* invd   = (float*)alloc((size_t)N * 4);
  int*   bsum   = (int*)alloc((size_t)NBLK * 4);
  const size_t FB = (size_t)N * 64 * 4;
  float* x  = (float*)alloc(FB);
  float* h0 = (float*)alloc(FB);
  float* h1 = (float*)alloc(FB);
  float* h2 = (float*)alloc(FB);
  float* m0 = (float*)alloc(FB);
  float* m1 = (float*)alloc(FB);
  float* m2 = (float*)alloc(FB);
  float* t0 = m2;                 // pre-MLP hidden; dead before m2 is written
  float* sv = (float*)alloc(256 * 4);

  hipMemsetAsync(cnt, 0, (size_t)N * 4, stream);
  hipMemsetAsync(sv, 0, 256 * 4, stream);

  const int* e_src = ei;
  const int* e_dst = ei + E;
  k_deg<<<(E + 255) / 256, 256, 0, stream>>>(e_dst, E, cnt);
  k_blockred<<<NBLK, 256, 0, stream>>>(cnt, N, bsum);
  k_scanb<<<1, 256, 0, stream>>>(bsum, NBLK, offs + N);   // writes offs[N] = E total
  k_scanfinal<<<NBLK, 256, 0, stream>>>(cnt, N, bsum, offs, cursor, invd);
  k_scatter<<<(E + 255) / 256, 256, 0, stream>>>(e_src, e_dst, E, cursor, csr);

  const int LGRID = (N + 63) / 64;
  auto lin = [&](int nsrc,
                 const float* a0, int s0, const float* w0, int g0,
                 const float* a1, int s1, const float* w1_, int g1,
                 const float* a2, int s2, const float* w2_, int g2,
                 const float* a3, int s3, const float* w3_, int g3,
                 const float* a4, int s4, const float* w4_, int g4,
                 const float* a5, int s5, const float* w5_, int g5,
                 const float* bias, float* outp, int relu) {
    LinArgs A;
    A.a[0] = a0; A.a[1] = a1; A.a[2] = a2; A.a[3] = a3; A.a[4] = a4; A.a[5] = a5;
    A.w[0] = w0; A.w[1] = w1_; A.w[2] = w2_; A.w[3] = w3_; A.w[4] = w4_; A.w[5] = w5_;
    A.gidx[0] = g0; A.gidx[1] = g1; A.gidx[2] = g2; A.gidx[3] = g3; A.gidx[4] = g4; A.gidx[5] = g5;
    A.stride[0] = s0; A.stride[1] = s1; A.stride[2] = s2; A.stride[3] = s3; A.stride[4] = s4; A.stride[5] = s5;
    A.nsrc = nsrc; A.bias = bias; A.skip = skip; A.out = outp; A.n = N; A.relu = relu;
    k_linear<<<LGRID, 256, 0, stream>>>(A);
  };

  // pre_mlp: t0 = relu(nf @ pre_w1 + pre_b1)   (K=128 -> two 64-row blocks)
  lin(2, nf, 128, pre_w1, -1, nf + 64, 128, pre_w1 + 64 * 64, -1,
      nullptr, 0, nullptr, -1, nullptr, 0, nullptr, -1, nullptr, 0, nullptr, -1,
      nullptr, 0, nullptr, -1, pre_b1, t0, 1);
  // x = t0 @ pre_w2 + pre_b2
  lin(1, t0, 64, pre_w2, -1,
      nullptr, 0, nullptr, -1, nullptr, 0, nullptr, -1, nullptr, 0, nullptr, -1,
      nullptr, 0, nullptr, -1, nullptr, 0, nullptr, -1, pre_b2, x, 0);

  // layer 0
  k_aggregate<<<(N + 3) / 4, 256, 0, stream>>>(x, offs, csr, invd, m0, N);
  lin(2, m0, 64, wl0, 0, x, 64, wr0, 0,
      nullptr, 0, nullptr, -1, nullptr, 0, nullptr, -1, nullptr, 0, nullptr, -1,
      nullptr, 0, nullptr, -1, bl0, h0, 1);

  // layer 1 (gates skip[1][0]=idx3, skip[1][1]=idx4)
  k_aggregate<<<(N + 3) / 4, 256, 0, stream>>>(h0, offs, csr, invd, m1, N);
  lin(4, m0, 64, wl1, 3, m1, 64, wl1 + 64 * 64, 4,
      x, 64, wr1, 3, h0, 64, wr1 + 64 * 64, 4,
      nullptr, 0, nullptr, -1, nullptr, 0, nullptr, -1, bl1, h1, 1);

  // layer 2 (gates skip[2][0..2] = idx 6,7,8)
  k_aggregate<<<(N + 3) / 4, 256, 0, stream>>>(h1, offs, csr, invd, m2, N);
  lin(6, m0, 64, wl2, 6, m1, 64, wl2 + 64 * 64, 7, m2, 64, wl2 + 128 * 64, 8,
      x, 64, wr2, 6, h0, 64, wr2 + 64 * 64, 7, h1, 64, wr2 + 128 * 64, 8,
      bl2, h2, 1);

  // s = column sums of [x|h0|h1|h2]; then post-MLP
  k_colsum<<<256, 256, 0, stream>>>(x, h0, h1, h2, N, sv);
  k_post<<<1, 256, 0, stream>>>(sv, pw1, pb1, pw2, pb2, pw3, pb3, pw4, pb4, out);
}